// Round 11
// baseline (46.611 us; speedup 1.0000x reference)
//
#include <hip/hip_runtime.h>
#include <hip/hip_bf16.h>
#include <math.h>

// Problem constants
#define B_   32
#define N_   64
#define D_   256
#define E_   32
#define DN_  64
#define H_   8
#define M_   32
#define HM_  256      // H_*M_
#define BN_  2048     // B_*N_
#define EPS_ 1e-5f
#define SQRT2_    1.41421356237309515f
#define NINVSQ2_ (-0.70710678118654752f)

typedef float f32x4 __attribute__((ext_vector_type(4)));
typedef short bf16x8 __attribute__((ext_vector_type(8)));
union U4S8 { uint4 u; bf16x8 s; };

// RNE pack of two f32 -> u32 of 2 bf16 (low = a); emits v_cvt_pk_bf16_f32.
__device__ __forceinline__ unsigned pk2(float a, float b) {
    union { __hip_bfloat162 h; unsigned u; } cv;
    cv.h = __float22bfloat162_rn(make_float2(a, b));
    return cv.u;
}

// MFMA conventions (validated rounds 2-10 on-device):
//  A-frag: lane = row (l&15), k-elem bijection g(hi,e)=hi*8+e (hi=l>>4)
//  B-frag: lane = col (l&15), same bijection
//  C/D   : col = lane&15, row = (lane>>4)*4 + reg
// Packed-weight layout (validated R7): frag f = ks*16 + c16 (c16 = 16-col tile),
//  P[f*64+l] = uint4 of 8 bf16 { W[ks*32+(l>>4)*8+e][c16*16+(l&15)] * scale }.
// Scales folded: Wr,Ws *= sqrt2 ; Wrn,Wsn *= -1/sqrt2 ; We *= 1.
// Gate factorization (validated R8-R10): g_rr = {U=e^{sqrt2*recv}, P=e^{-rn/sqrt2}},
//  g_ssC = {V=e^{sqrt2*send}, Q=e^{-sn/sqrt2}} (sender-compacted); u=U*V, v=P*Q,
//  tanh*sigmoid = (u-1)*rcp((u+1)(v+1)); pad rows V=Q=0 -> g=-1, ep=0 -> 0.

__device__ __forceinline__ void remap(int wg, int& b, int& s) {
    const int xcd = wg & 7;              // XCD-affine, bijective on [0,512)
    b = xcd * 4 + (wg >> 7);
    s = (wg >> 3) & 15;
}

// mask utilities: detect int32 vs byte-bool layout, ballot per batch
__device__ __forceinline__ unsigned long long mask_bits(
        const int* mraw, int b, int t, int w, int l, int* s_flag_sh,
        unsigned long long* bits_sh) {
    if (t == 0) *s_flag_sh = 0;
    __syncthreads();
    { int v0 = mraw[t], v1 = mraw[t + 256];
      if (((v0 | v1) & ~1) != 0) atomicOr(s_flag_sh, 1); }
    __syncthreads();
    const bool bytef = (*s_flag_sh != 0);
    const unsigned char* mbb = (const unsigned char*)mraw;
    if (w == 0) {
        const int k = b * N_ + l;
        const bool on = bytef ? (mbb[k] != 0) : (mraw[k] != 0);
        unsigned long long bits = __ballot(on);
        if (l == 0) *bits_sh = bits;
    }
    __syncthreads();
    return *bits_sh;
}

// ---------------------------------------------------------------------------
// K0: weight pre-pack, 84 blocks (Wr 32, Ws 32, Wrn 8, Wsn 8, We 4).
// Converts all 5 weight matrices to bf16 MFMA B-fragment layout with the gate
// scale factors folded in. ~660 KB read, trivially fast.
// ---------------------------------------------------------------------------
__global__ __launch_bounds__(256) void pre_k(
        const float* __restrict__ Wr, const float* __restrict__ Ws,
        const float* __restrict__ Wrn, const float* __restrict__ Wsn,
        const float* __restrict__ We,
        uint4* __restrict__ WrP, uint4* __restrict__ WsP,
        uint4* __restrict__ WrnP, uint4* __restrict__ WsnP,
        uint4* __restrict__ WeP)
{
    const int pb = blockIdx.x, t = threadIdx.x;
    const float* src; uint4* dst; float sc; int tloc;
    if (pb < 32)      { src = Wr;  dst = WrP;  sc = SQRT2_;   tloc = pb; }
    else if (pb < 64) { src = Ws;  dst = WsP;  sc = SQRT2_;   tloc = pb - 32; }
    else if (pb < 72) { src = Wrn; dst = WrnP; sc = NINVSQ2_; tloc = pb - 64; }
    else if (pb < 80) { src = Wsn; dst = WsnP; sc = NINVSQ2_; tloc = pb - 72; }
    else              { src = We;  dst = WeP;  sc = 1.0f;     tloc = pb - 80; }
    const int tau = tloc * 256 + t;
    const int f = tau >> 6, l = tau & 63;
    const int n  = (f & 15) * 16 + (l & 15);
    const int k0 = (f >> 4) * 32 + (l >> 4) * 8;
    const float* p = src + (size_t)k0 * HM_ + n;
    dst[f * 64 + l] = make_uint4(pk2(p[0]*sc,      p[HM_]*sc),
                                 pk2(p[2*HM_]*sc,  p[3*HM_]*sc),
                                 pk2(p[4*HM_]*sc,  p[5*HM_]*sc),
                                 pk2(p[6*HM_]*sc,  p[7*HM_]*sc));
}

// ---------------------------------------------------------------------------
// K1: node kernel. 512 blocks = (b, 16-ch slice s). A-fragments built
// register-direct from emb/nfeat (row-parallel LN stats); B-fragments are
// single coalesced uint4 loads from the packed weights. 20 MFMAs/wave.
// ---------------------------------------------------------------------------
__global__ __launch_bounds__(256, 4) void node_k(
        const float* __restrict__ emb, const float* __restrict__ nfeat,
        const int* __restrict__ mraw,
        const uint4* __restrict__ WrP, const uint4* __restrict__ WsP,
        const uint4* __restrict__ WrnP, const uint4* __restrict__ WsnP,
        float2* __restrict__ g_rr, float2* __restrict__ g_ssC) {
    const int t = threadIdx.x;
    const int w = t >> 6, l = t & 63, hi = l >> 4, lo = l & 15;
    int b, s; remap(blockIdx.x, b, s);

    __shared__ int s_flag;
    __shared__ unsigned long long bits_sh;
    const unsigned long long bits = mask_bits(mraw, b, t, w, l, &s_flag, &bits_sh);
    const int cb = __popcll(bits);

    // --- row-parallel LN stats: 4 lanes per row (rows w*16 .. w*16+15)
    float mu_l, rs_l;
    {
        const int qrow = w * 16 + (l >> 2);
        const float* rp = emb + (size_t)(b * N_ + qrow) * D_ + (l & 3) * 64;
        float sv = 0.f, s2 = 0.f;
        #pragma unroll
        for (int k = 0; k < 16; ++k) {
            float4 x = *(const float4*)(rp + k * 4);
            sv += x.x + x.y + x.z + x.w;
            s2 += x.x*x.x + x.y*x.y + x.z*x.z + x.w*x.w;
        }
        sv += __shfl_xor(sv, 1); sv += __shfl_xor(sv, 2);
        s2 += __shfl_xor(s2, 1); s2 += __shfl_xor(s2, 2);
        float mu  = sv * (1.0f / D_);
        float var = s2 * (1.0f / D_) - mu * mu;
        float rs  = rsqrtf(var + EPS_) * (((bits >> qrow) & 1ull) ? 1.0f : 0.0f);
        mu_l = __shfl(mu, lo << 2);
        rs_l = __shfl(rs, lo << 2);
    }

    // --- node GEMM for ch slice s: rows w*16..+15, packed-weight B-frags
    const int nb = s * 16 + lo;
    const float* arow = emb   + (size_t)(b * N_ + w * 16 + lo) * D_  + hi * 8;
    const float* nrow = nfeat + (size_t)(b * N_ + w * 16 + lo) * DN_ + hi * 8;
    f32x4 aR = {0,0,0,0}, aS = {0,0,0,0}, aRN = {0,0,0,0}, aSN = {0,0,0,0};
    #pragma unroll
    for (int ks = 0; ks < 8; ++ks) {
        float4 xa = *(const float4*)(arow + ks * 32);
        float4 xb = *(const float4*)(arow + ks * 32 + 4);
        U4S8 a;
        a.u = make_uint4(pk2((xa.x - mu_l) * rs_l, (xa.y - mu_l) * rs_l),
                         pk2((xa.z - mu_l) * rs_l, (xa.w - mu_l) * rs_l),
                         pk2((xb.x - mu_l) * rs_l, (xb.y - mu_l) * rs_l),
                         pk2((xb.z - mu_l) * rs_l, (xb.w - mu_l) * rs_l));
        U4S8 br, bs;
        br.u = WrP[(ks * 16 + s) * 64 + l];
        bs.u = WsP[(ks * 16 + s) * 64 + l];
        aR = __builtin_amdgcn_mfma_f32_16x16x32_bf16(a.s, br.s, aR, 0, 0, 0);
        aS = __builtin_amdgcn_mfma_f32_16x16x32_bf16(a.s, bs.s, aS, 0, 0, 0);
        if (ks < 2) {
            float4 na  = *(const float4*)(nrow + ks * 32);
            float4 nb4 = *(const float4*)(nrow + ks * 32 + 4);
            U4S8 a2;
            a2.u = make_uint4(pk2(na.x, na.y),   pk2(na.z, na.w),
                              pk2(nb4.x, nb4.y), pk2(nb4.z, nb4.w));
            U4S8 brn, bsn;
            brn.u = WrnP[(ks * 16 + s) * 64 + l];
            bsn.u = WsnP[(ks * 16 + s) * 64 + l];
            aRN = __builtin_amdgcn_mfma_f32_16x16x32_bf16(a2.s, brn.s, aRN, 0, 0, 0);
            aSN = __builtin_amdgcn_mfma_f32_16x16x32_bf16(a2.s, bsn.s, aSN, 0, 0, 0);
        }
    }

    // --- exp epilogue (scales already folded into weights) + coalesced stores
    #pragma unroll
    for (int r = 0; r < 4; ++r) {
        const int i = w * 16 + hi * 4 + r;
        g_rr[(size_t)(b * N_ + i) * HM_ + nb] =
            make_float2(__expf(aR[r]), __expf(aRN[r]));
        if ((bits >> i) & 1ull) {
            const int p = __popcll(bits & ((1ull << i) - 1ull));
            g_ssC[(size_t)(b * N_ + p) * HM_ + nb] =
                make_float2(__expf(aS[r]), __expf(aSN[r]));
        }
    }
    for (int p = cb + (t >> 4); p < N_; p += 16)    // zero-fill pad sender rows
        g_ssC[(size_t)(b * N_ + p) * HM_ + s * 16 + (t & 15)] = make_float2(0.f, 0.f);
}

// ---------------------------------------------------------------------------
// K2: edge kernel. 512 blocks = (b, receivers j0..j0+3). Packed We B-frags
// (4 coalesced loads). Otherwise R10's validated body.
// ---------------------------------------------------------------------------
__global__ __launch_bounds__(256, 4) void edge_k(
        const float* __restrict__ edge, const uint4* __restrict__ WeP,
        const int* __restrict__ mraw,
        const float2* __restrict__ g_rr, const float2* __restrict__ g_ssC,
        float* __restrict__ out) {
    const int t = threadIdx.x;
    const int w = t >> 6, l = t & 63, hi = l >> 4, lo = l & 15;
    int b, s; remap(blockIdx.x, b, s);
    const int j0 = s * 4;

    __shared__ int s_flag;
    __shared__ unsigned long long bits_sh;
    __shared__ int sidx_s[N_];
    __shared__ __align__(16) uint4 ldsA[4][256];   // 16 KB edge A-tiles

    const unsigned long long bits = mask_bits(mraw, b, t, w, l, &s_flag, &bits_sh);
    const int cb = __popcll(bits);
    if (w == 0) {                    // compaction table
        const bool on = (bits >> l) & 1ull;
        int p = __popcll(bits & ((1ull << l) - 1ull));
        if (on) sidx_s[p] = l;
        if (l >= cb) sidx_s[l] = -1;
    }
    __syncthreads();

    if (((bits >> j0) & 15ull) == 0ull) {           // all 4 receivers masked
        #pragma unroll
        for (int q = 0; q < 4; ++q)
            out[(size_t)(b * N_ + j0 + q) * HM_ + t] = 0.0f;
        return;
    }

    {   // pack A fragments for the 4 receivers (compacted senders)
        const int mt = t >> 6, phi = (t >> 4) & 3, plo = t & 15;
        const int si = sidx_s[mt * 16 + plo];
        if (si >= 0) {
            const float* rb = edge + ((size_t)((b * N_ + si) * N_ + j0)) * E_ + phi * 8;
            #pragma unroll
            for (int q = 0; q < 4; ++q) {
                float4 v0 = *(const float4*)(rb + q * E_);
                float4 v1 = *(const float4*)(rb + q * E_ + 4);
                ldsA[q][t] = make_uint4(pk2(v0.x, v0.y), pk2(v0.z, v0.w),
                                        pk2(v1.x, v1.y), pk2(v1.z, v1.w));
            }
        } else {
            #pragma unroll
            for (int q = 0; q < 4; ++q) ldsA[q][t] = make_uint4(0, 0, 0, 0);
        }
    }
    __syncthreads();

    // W_edge B-fragments: coalesced packed loads
    U4S8 b4[4];
    #pragma unroll
    for (int nl = 0; nl < 4; ++nl) b4[nl].u = WeP[(w * 4 + nl) * 64 + l];

    float2 rrq[4][4];
    #pragma unroll
    for (int q = 0; q < 4; ++q)
        #pragma unroll
        for (int nl = 0; nl < 4; ++nl)
            rrq[q][nl] = g_rr[(size_t)(b * N_ + j0 + q) * HM_ + w * 64 + nl * 16 + lo];

    float upd[4][4];
    #pragma unroll
    for (int q = 0; q < 4; ++q)
        #pragma unroll
        for (int nl = 0; nl < 4; ++nl) upd[q][nl] = 0.0f;

    const f32x4 zero = {0.0f, 0.0f, 0.0f, 0.0f};
    #pragma unroll
    for (int mt = 0; mt < 4; ++mt) {
        if (mt * 16 < cb) {                         // wave-uniform subtile skip
            float2 ssv[4][4];
            #pragma unroll
            for (int r = 0; r < 4; ++r) {
                const float2* srow =
                    g_ssC + (size_t)(b * N_ + mt * 16 + hi * 4 + r) * HM_ + w * 64 + lo;
                #pragma unroll
                for (int nl = 0; nl < 4; ++nl) ssv[r][nl] = srow[nl * 16];
            }
            #pragma unroll
            for (int q = 0; q < 4; ++q) {
                if ((bits >> (j0 + q)) & 1ull) {    // receiver unmasked
                    U4S8 a; a.u = ldsA[q][mt * 64 + l];
                    f32x4 acc[4];
                    #pragma unroll
                    for (int nl = 0; nl < 4; ++nl)
                        acc[nl] = __builtin_amdgcn_mfma_f32_16x16x32_bf16(a.s, b4[nl].s, zero, 0, 0, 0);
                    #pragma unroll
                    for (int r = 0; r < 4; ++r)
                        #pragma unroll
                        for (int nl = 0; nl < 4; ++nl) {
                            float u = rrq[q][nl].x * ssv[r][nl].x;   // e^{2a}
                            float v = rrq[q][nl].y * ssv[r][nl].y;   // e^{-z}
                            float den = (u + 1.0f) * (v + 1.0f);
                            float g = (u - 1.0f) * __builtin_amdgcn_rcpf(den);
                            upd[q][nl] = fmaf(g, acc[nl][r], upd[q][nl]);
                        }
                }
            }
        }
    }
    #pragma unroll
    for (int q = 0; q < 4; ++q) {
        const int j = j0 + q, bn = b * N_ + j;
        if (!((bits >> j) & 1ull)) {
            out[(size_t)bn * HM_ + w * 64 + l] = 0.0f;
            continue;
        }
        float u0 = upd[q][0], u1 = upd[q][1], u2 = upd[q][2], u3 = upd[q][3];
        u0 += __shfl_xor(u0, 16); u0 += __shfl_xor(u0, 32);
        u1 += __shfl_xor(u1, 16); u1 += __shfl_xor(u1, 32);
        u2 += __shfl_xor(u2, 16); u2 += __shfl_xor(u2, 32);
        u3 += __shfl_xor(u3, 16); u3 += __shfl_xor(u3, 32);
        float s0 = u0 + u1, q0 = u0*u0 + u1*u1;
        float s1 = u2 + u3, q1 = u2*u2 + u3*u3;
        #pragma unroll
        for (int k = 8; k >= 1; k >>= 1) {
            s0 += __shfl_xor(s0, k); q0 += __shfl_xor(q0, k);
            s1 += __shfl_xor(s1, k); q1 += __shfl_xor(q1, k);
        }
        float mu0 = s0 * (1.0f / M_), va0 = q0 * (1.0f / M_) - mu0 * mu0;
        float mu1 = s1 * (1.0f / M_), va1 = q1 * (1.0f / M_) - mu1 * mu1;
        float rs0 = rsqrtf(va0 + EPS_), rs1 = rsqrtf(va1 + EPS_);
        float v01 = (hi & 1) ? u1 : u0;
        float v23 = (hi & 1) ? u3 : u2;
        float val = (hi < 2) ? v01 : v23;           // static select
        float o = (hi < 2) ? (val - mu0) * rs0 : (val - mu1) * rs1;
        out[(size_t)bn * HM_ + w * 64 + l] = o;
    }
}

// ---------------------------------------------------------------------------
extern "C" void kernel_launch(void* const* d_in, const int* in_sizes, int n_in,
                              void* d_out, int out_size, void* d_ws, size_t ws_size,
                              hipStream_t stream) {
    const float* embeddings = (const float*)d_in[0];
    const float* edge_feat  = (const float*)d_in[1];
    const int*   mask_raw   = (const int*)d_in[2];
    const float* node_feat  = (const float*)d_in[3];
    const float* W_edge     = (const float*)d_in[4];
    const float* W_recv     = (const float*)d_in[5];
    const float* W_send     = (const float*)d_in[6];
    const float* W_recvn    = (const float*)d_in[7];
    const float* W_sendn    = (const float*)d_in[8];
    float* out = (float*)d_out;

    // workspace layout (~8.4 MB)
    float2* g_ssC = (float2*)d_ws;                        // 4 MB
    float2* g_rr  = g_ssC + (size_t)BN_ * HM_;            // 4 MB
    uint4* WrP  = (uint4*)(g_rr + (size_t)BN_ * HM_);     // 128 KB
    uint4* WsP  = WrP + 8192;                             // 128 KB
    uint4* WrnP = WsP + 8192;                             // 32 KB
    uint4* WsnP = WrnP + 2048;                            // 32 KB
    uint4* WeP  = WsnP + 2048;                            // 16 KB

    pre_k<<<84, 256, 0, stream>>>(W_recv, W_send, W_recvn, W_sendn, W_edge,
                                  WrP, WsP, WrnP, WsnP, WeP);
    node_k<<<512, 256, 0, stream>>>(embeddings, node_feat, mask_raw,
                                    WrP, WsP, WrnP, WsnP, g_rr, g_ssC);
    edge_k<<<512, 256, 0, stream>>>(edge_feat, WeP, mask_raw,
                                    g_rr, g_ssC, out);
}

// Round 12
// 39.062 us; speedup vs baseline: 1.1932x; 1.1932x over previous
//
#include <hip/hip_runtime.h>
#include <hip/hip_bf16.h>
#include <math.h>

// Problem constants
#define B_   32
#define N_   64
#define D_   256
#define E_   32
#define DN_  64
#define H_   8
#define M_   32
#define HM_  256      // H_*M_
#define BN_  2048     // B_*N_
#define EPS_ 1e-5f
#define SQRT2_    1.41421356237309515f
#define NINVSQ2_ (-0.70710678118654752f)

typedef float f32x4 __attribute__((ext_vector_type(4)));
typedef short bf16x8 __attribute__((ext_vector_type(8)));
union U4S8 { uint4 u; bf16x8 s; };

// RNE pack of two f32 -> u32 of 2 bf16 (low = a); emits v_cvt_pk_bf16_f32.
__device__ __forceinline__ unsigned pk2(float a, float b) {
    union { __hip_bfloat162 h; unsigned u; } cv;
    cv.h = __float22bfloat162_rn(make_float2(a, b));
    return cv.u;
}

// MFMA conventions (validated rounds 2-11 on-device):
//  A-frag: lane = row (l&15), k-elem bijection g(hi,e)=hi*8+e (hi=l>>4)
//  B-frag: lane = col (l&15), same bijection
//  C/D   : col = lane&15, row = (lane>>4)*4 + reg
// Gate factorization (validated R8-R11): g_rr = {U=e^{sqrt2*recv}, P=e^{-rn/sqrt2}},
//  g_ssC = {V=e^{sqrt2*send}, Q=e^{-sn/sqrt2}} (sender-compacted); u=U*V, v=P*Q,
//  tanh*sigmoid = (u-1)*rcp((u+1)(v+1)); pad rows V=Q=0 -> g=-1, ep=0 -> 0.
//
// R12 structural change (latency-bound diagnosis from R9 counters):
//  both kernels re-partitioned for 4096 waves (4 waves/SIMD) instead of 2048.

// XCD-affine remaps (bijective): all blocks of batch b land on one XCD.
__device__ __forceinline__ void remap512(int wg, int& b, int& s) {
    b = (wg & 7) * 4 + (wg >> 7);        // xcd*4 + top2
    s = (wg >> 3) & 15;
}
__device__ __forceinline__ void remap1024(int wg, int& b, int& s) {
    b = (wg & 7) * 4 + (wg >> 8);        // xcd*4 + top2
    s = (wg >> 3) & 31;
}

// mask utilities: detect int32 vs byte-bool layout, ballot per batch.
// Detection reads stay within the first 2048 bytes for any block size.
__device__ __forceinline__ unsigned long long mask_bits(
        const int* mraw, int b, int t, int w, int l, int* s_flag_sh,
        unsigned long long* bits_sh) {
    if (t == 0) *s_flag_sh = 0;
    __syncthreads();
    { const int ti = t & 255;
      int v0 = mraw[ti], v1 = mraw[ti + 256];
      if (((v0 | v1) & ~1) != 0) atomicOr(s_flag_sh, 1); }
    __syncthreads();
    const bool bytef = (*s_flag_sh != 0);
    const unsigned char* mbb = (const unsigned char*)mraw;
    if (w == 0) {
        const int k = b * N_ + l;
        const bool on = bytef ? (mbb[k] != 0) : (mraw[k] != 0);
        unsigned long long bits = __ballot(on);
        if (l == 0) *bits_sh = bits;
    }
    __syncthreads();
    return *bits_sh;
}

// ---------------------------------------------------------------------------
// K1: node kernel. 512 blocks x 512 threads = (b, 16-ch slice s).
// Waves 0-3: recv/rn GEMM for row-tile w. Waves 4-7: send/sn GEMM for
// row-tile w-4. 10 MFMAs/wave; 4096 waves total (4/SIMD).
// ---------------------------------------------------------------------------
__global__ __launch_bounds__(512, 4) void node_k(
        const float* __restrict__ emb, const float* __restrict__ nfeat,
        const int* __restrict__ mraw,
        const float* __restrict__ Wr, const float* __restrict__ Ws,
        const float* __restrict__ Wrn, const float* __restrict__ Wsn,
        float2* __restrict__ g_rr, float2* __restrict__ g_ssC) {
    const int t = threadIdx.x;
    const int w = t >> 6, l = t & 63, hi = l >> 4, lo = l & 15;
    const int rt = w & 3;                // row-tile
    const int sendside = w >> 2;         // 0: recv/rn, 1: send/sn
    int b, s; remap512(blockIdx.x, b, s);

    __shared__ int s_flag;
    __shared__ unsigned long long bits_sh;
    const unsigned long long bits = mask_bits(mraw, b, t, w, l, &s_flag, &bits_sh);
    const int cb = __popcll(bits);

    // --- row-parallel LN stats for rows rt*16 .. rt*16+15 (4 lanes per row)
    float mu_l, rs_l;
    {
        const int qrow = rt * 16 + (l >> 2);
        const float* rp = emb + (size_t)(b * N_ + qrow) * D_ + (l & 3) * 64;
        float sv = 0.f, s2 = 0.f;
        #pragma unroll
        for (int k = 0; k < 16; ++k) {
            float4 x = *(const float4*)(rp + k * 4);
            sv += x.x + x.y + x.z + x.w;
            s2 += x.x*x.x + x.y*x.y + x.z*x.z + x.w*x.w;
        }
        sv += __shfl_xor(sv, 1); sv += __shfl_xor(sv, 2);
        s2 += __shfl_xor(s2, 1); s2 += __shfl_xor(s2, 2);
        float mu  = sv * (1.0f / D_);
        float var = s2 * (1.0f / D_) - mu * mu;
        float rs  = rsqrtf(var + EPS_) * (((bits >> qrow) & 1ull) ? 1.0f : 0.0f);
        mu_l = __shfl(mu, lo << 2);
        rs_l = __shfl(rs, lo << 2);
    }

    // --- GEMM for this side: rows rt*16..+15, channels s*16..+15
    const float* W1 = sendside ? Ws  : Wr;    // wave-uniform selects
    const float* W2 = sendside ? Wsn : Wrn;
    const int nb = s * 16 + lo;
    const float* arow = emb   + (size_t)(b * N_ + rt * 16 + lo) * D_  + hi * 8;
    const float* nrow = nfeat + (size_t)(b * N_ + rt * 16 + lo) * DN_ + hi * 8;
    f32x4 a1 = {0,0,0,0}, a2 = {0,0,0,0};
    #pragma unroll
    for (int ks = 0; ks < 8; ++ks) {
        float4 xa = *(const float4*)(arow + ks * 32);
        float4 xb = *(const float4*)(arow + ks * 32 + 4);
        U4S8 a;
        a.u = make_uint4(pk2((xa.x - mu_l) * rs_l, (xa.y - mu_l) * rs_l),
                         pk2((xa.z - mu_l) * rs_l, (xa.w - mu_l) * rs_l),
                         pk2((xb.x - mu_l) * rs_l, (xb.y - mu_l) * rs_l),
                         pk2((xb.z - mu_l) * rs_l, (xb.w - mu_l) * rs_l));
        const float* wp = W1 + (size_t)(ks * 32 + hi * 8) * HM_ + nb;
        U4S8 bfr;
        bfr.u = make_uint4(pk2(wp[0],     wp[HM_]),    pk2(wp[2*HM_], wp[3*HM_]),
                           pk2(wp[4*HM_], wp[5*HM_]),  pk2(wp[6*HM_], wp[7*HM_]));
        a1 = __builtin_amdgcn_mfma_f32_16x16x32_bf16(a.s, bfr.s, a1, 0, 0, 0);
        if (ks < 2) {
            float4 na  = *(const float4*)(nrow + ks * 32);
            float4 nb4 = *(const float4*)(nrow + ks * 32 + 4);
            U4S8 an;
            an.u = make_uint4(pk2(na.x, na.y),   pk2(na.z, na.w),
                              pk2(nb4.x, nb4.y), pk2(nb4.z, nb4.w));
            const float* wn = W2 + (size_t)(ks * 32 + hi * 8) * HM_ + nb;
            U4S8 bn;
            bn.u = make_uint4(pk2(wn[0],     wn[HM_]),    pk2(wn[2*HM_], wn[3*HM_]),
                              pk2(wn[4*HM_], wn[5*HM_]),  pk2(wn[6*HM_], wn[7*HM_]));
            a2 = __builtin_amdgcn_mfma_f32_16x16x32_bf16(an.s, bn.s, a2, 0, 0, 0);
        }
    }

    // --- exp epilogue + coalesced stores
    #pragma unroll
    for (int r = 0; r < 4; ++r) {
        const int i = rt * 16 + hi * 4 + r;
        float2 v = make_float2(__expf(SQRT2_ * a1[r]), __expf(NINVSQ2_ * a2[r]));
        if (sendside == 0) {
            g_rr[(size_t)(b * N_ + i) * HM_ + nb] = v;
        } else if ((bits >> i) & 1ull) {
            const int p = __popcll(bits & ((1ull << i) - 1ull));
            g_ssC[(size_t)(b * N_ + p) * HM_ + nb] = v;
        }
    }
    if (sendside) {                      // zero-fill pad sender rows
        const int tt = t - 256;
        for (int p = cb + (tt >> 4); p < N_; p += 16)
            g_ssC[(size_t)(b * N_ + p) * HM_ + s * 16 + (tt & 15)] = make_float2(0.f, 0.f);
    }
}

// ---------------------------------------------------------------------------
// K2: edge kernel. 1024 blocks x 256 threads = (b, receiver pair j0, j0+1).
// 4096 waves (4/SIMD). Per-r-scoped ssv loads keep VGPRs <= ~110.
// ---------------------------------------------------------------------------
__global__ __launch_bounds__(256, 4) void edge_k(
        const float* __restrict__ edge, const float* __restrict__ We,
        const int* __restrict__ mraw,
        const float2* __restrict__ g_rr, const float2* __restrict__ g_ssC,
        float* __restrict__ out) {
    const int t = threadIdx.x;
    const int w = t >> 6, l = t & 63, hi = l >> 4, lo = l & 15;
    int b, s; remap1024(blockIdx.x, b, s);
    const int j0 = s * 2;

    __shared__ int s_flag;
    __shared__ unsigned long long bits_sh;
    __shared__ int sidx_s[N_];
    __shared__ __align__(16) uint4 ldsA[2][256];   // 8 KB edge A-tiles

    const unsigned long long bits = mask_bits(mraw, b, t, w, l, &s_flag, &bits_sh);
    const int cb = __popcll(bits);
    if (w == 0) {                    // compaction table
        const bool on = (bits >> l) & 1ull;
        int p = __popcll(bits & ((1ull << l) - 1ull));
        if (on) sidx_s[p] = l;
        if (l >= cb) sidx_s[l] = -1;
    }
    __syncthreads();

    if (((bits >> j0) & 3ull) == 0ull) {            // both receivers masked
        #pragma unroll
        for (int q = 0; q < 2; ++q)
            out[(size_t)(b * N_ + j0 + q) * HM_ + t] = 0.0f;
        return;
    }

    {   // pack A fragments for the 2 receivers (compacted senders)
        const int mt = t >> 6, phi = (t >> 4) & 3, plo = t & 15;
        const int si = sidx_s[mt * 16 + plo];
        if (si >= 0) {
            const float* rb = edge + ((size_t)((b * N_ + si) * N_ + j0)) * E_ + phi * 8;
            #pragma unroll
            for (int q = 0; q < 2; ++q) {
                float4 v0 = *(const float4*)(rb + q * E_);
                float4 v1 = *(const float4*)(rb + q * E_ + 4);
                ldsA[q][t] = make_uint4(pk2(v0.x, v0.y), pk2(v0.z, v0.w),
                                        pk2(v1.x, v1.y), pk2(v1.z, v1.w));
            }
        } else {
            #pragma unroll
            for (int q = 0; q < 2; ++q) ldsA[q][t] = make_uint4(0, 0, 0, 0);
        }
    }
    __syncthreads();

    // W_edge B-fragments (block-invariant, L2-hot; prepack proved neutral R11)
    U4S8 b4[4];
    #pragma unroll
    for (int nl = 0; nl < 4; ++nl) {
        const float* wp = We + (size_t)(hi * 8) * HM_ + w * 64 + nl * 16 + lo;
        b4[nl].u = make_uint4(pk2(wp[0],     wp[HM_]),    pk2(wp[2*HM_], wp[3*HM_]),
                              pk2(wp[4*HM_], wp[5*HM_]),  pk2(wp[6*HM_], wp[7*HM_]));
    }

    float2 rrq[2][4];
    #pragma unroll
    for (int q = 0; q < 2; ++q)
        #pragma unroll
        for (int nl = 0; nl < 4; ++nl)
            rrq[q][nl] = g_rr[(size_t)(b * N_ + j0 + q) * HM_ + w * 64 + nl * 16 + lo];

    float upd[2][4];
    #pragma unroll
    for (int q = 0; q < 2; ++q)
        #pragma unroll
        for (int nl = 0; nl < 4; ++nl) upd[q][nl] = 0.0f;

    const f32x4 zero = {0.0f, 0.0f, 0.0f, 0.0f};
    #pragma unroll
    for (int mt = 0; mt < 4; ++mt) {
        if (mt * 16 < cb) {                         // wave-uniform subtile skip
            f32x4 acc[2][4];
            #pragma unroll
            for (int q = 0; q < 2; ++q) {
                U4S8 a; a.u = ldsA[q][mt * 64 + l];
                #pragma unroll
                for (int nl = 0; nl < 4; ++nl)
                    acc[q][nl] = __builtin_amdgcn_mfma_f32_16x16x32_bf16(a.s, b4[nl].s, zero, 0, 0, 0);
            }
            #pragma unroll
            for (int r = 0; r < 4; ++r) {
                const float2* srow =
                    g_ssC + (size_t)(b * N_ + mt * 16 + hi * 4 + r) * HM_ + w * 64 + lo;
                float2 ssv[4];
                #pragma unroll
                for (int nl = 0; nl < 4; ++nl) ssv[nl] = srow[nl * 16];
                #pragma unroll
                for (int q = 0; q < 2; ++q)
                    #pragma unroll
                    for (int nl = 0; nl < 4; ++nl) {
                        float u = rrq[q][nl].x * ssv[nl].x;   // e^{2a}
                        float v = rrq[q][nl].y * ssv[nl].y;   // e^{-z}
                        float den = (u + 1.0f) * (v + 1.0f);
                        float g = (u - 1.0f) * __builtin_amdgcn_rcpf(den);
                        upd[q][nl] = fmaf(g, acc[q][nl][r], upd[q][nl]);
                    }
            }
        }
    }
    #pragma unroll
    for (int q = 0; q < 2; ++q) {
        const int j = j0 + q, bn = b * N_ + j;
        if (!((bits >> j) & 1ull)) {
            out[(size_t)bn * HM_ + w * 64 + l] = 0.0f;
            continue;
        }
        float u0 = upd[q][0], u1 = upd[q][1], u2 = upd[q][2], u3 = upd[q][3];
        u0 += __shfl_xor(u0, 16); u0 += __shfl_xor(u0, 32);
        u1 += __shfl_xor(u1, 16); u1 += __shfl_xor(u1, 32);
        u2 += __shfl_xor(u2, 16); u2 += __shfl_xor(u2, 32);
        u3 += __shfl_xor(u3, 16); u3 += __shfl_xor(u3, 32);
        float s0 = u0 + u1, q0 = u0*u0 + u1*u1;
        float s1 = u2 + u3, q1 = u2*u2 + u3*u3;
        #pragma unroll
        for (int k = 8; k >= 1; k >>= 1) {
            s0 += __shfl_xor(s0, k); q0 += __shfl_xor(q0, k);
            s1 += __shfl_xor(s1, k); q1 += __shfl_xor(q1, k);
        }
        float mu0 = s0 * (1.0f / M_), va0 = q0 * (1.0f / M_) - mu0 * mu0;
        float mu1 = s1 * (1.0f / M_), va1 = q1 * (1.0f / M_) - mu1 * mu1;
        float rs0 = rsqrtf(va0 + EPS_), rs1 = rsqrtf(va1 + EPS_);
        float v01 = (hi & 1) ? u1 : u0;
        float v23 = (hi & 1) ? u3 : u2;
        float val = (hi < 2) ? v01 : v23;           // static select
        float o = (hi < 2) ? (val - mu0) * rs0 : (val - mu1) * rs1;
        out[(size_t)bn * HM_ + w * 64 + l] = o;
    }
}

// ---------------------------------------------------------------------------
extern "C" void kernel_launch(void* const* d_in, const int* in_sizes, int n_in,
                              void* d_out, int out_size, void* d_ws, size_t ws_size,
                              hipStream_t stream) {
    const float* embeddings = (const float*)d_in[0];
    const float* edge_feat  = (const float*)d_in[1];
    const int*   mask_raw   = (const int*)d_in[2];
    const float* node_feat  = (const float*)d_in[3];
    const float* W_edge     = (const float*)d_in[4];
    const float* W_recv     = (const float*)d_in[5];
    const float* W_send     = (const float*)d_in[6];
    const float* W_recvn    = (const float*)d_in[7];
    const float* W_sendn    = (const float*)d_in[8];
    float* out = (float*)d_out;

    // workspace layout (~8 MB)
    float2* g_ssC = (float2*)d_ws;                        // 4 MB
    float2* g_rr  = g_ssC + (size_t)BN_ * HM_;            // 4 MB

    node_k<<<512, 512, 0, stream>>>(embeddings, node_feat, mask_raw,
                                    W_recv, W_send, W_recvn, W_sendn,
                                    g_rr, g_ssC);
    edge_k<<<1024, 256, 0, stream>>>(edge_feat, W_edge, mask_raw,
                                     g_rr, g_ssC, out);
}